// Round 10
// baseline (129.336 us; speedup 1.0000x reference)
//
#include <hip/hip_runtime.h>

// Problem constants: B=8, N=128, T=64, EMBED=64, HEADS=8, HEAD_DIM=8
// V/K/Q/Out layout: (b, n, t, c) fp32, element strides (524288, 4096, 64, 1).
// Round-7: MFMA version ~38us. Round-8/9: deferred softmax normalization.
// Round-9 BUG: PV output rows are queries quad*4+r, but lane's inv is for query
// q16 (P's column). Fix: invr[r] = __shfl(inv, quad*4+r) — shuffles overlap the
// PV MFMA chain, preserving the latency win.

typedef _Float16 half4 __attribute__((ext_vector_type(4)));
typedef __fp16   fp16x2 __attribute__((ext_vector_type(2)));
typedef float    f32x4 __attribute__((ext_vector_type(4)));

#define MFMA16(a,b,c) __builtin_amdgcn_mfma_f32_16x16x16f16((a),(b),(c),0,0,0)

__device__ __forceinline__ unsigned short f2h(float f){
    union { _Float16 h; unsigned short u; } c; c.h = (_Float16)f; return c.u;
}
__device__ __forceinline__ unsigned int pk2(float a, float b){
    union { fp16x2 h; unsigned int u; } c;
    c.h = __builtin_amdgcn_cvt_pkrtz(a, b);
    return c.u;
}

// LDS offsets in halves. Total 38408 halves = 76816 B -> 2 blocks/CU.
#define ZS 0          // 8 halves zero scratch (b64 target for padded lanes)
#define KB 8          // K' per head: [128 k][8 d]
#define QB 8200       // Q' per head: [128 q][8 d] (pre-scaled by sc)
#define VB 16392      // V'^T per head: [8 e][128 k]
#define CB 24584      // C': [128 n][72]
#define WB 33800      // Wo: [64 o][72]
#define LDS_TOTAL 38408

__global__ __launch_bounds__(512, 4)
void sattn_kernel(const float* __restrict__ V,
                  const float* __restrict__ K,
                  const float* __restrict__ Q,
                  const float* __restrict__ Wv,
                  const float* __restrict__ Wk,
                  const float* __restrict__ Wq,
                  const float* __restrict__ Wo,
                  const float* __restrict__ bo,
                  float* __restrict__ Out)
{
    __shared__ __align__(16) unsigned short smem[LDS_TOTAL];

    const int tid  = threadIdx.x;
    const int bid  = blockIdx.x;
    const int b    = bid >> 6;
    const int t    = bid & 63;
    const long base = (long)b * 524288 + t * 64;
    const float SC = 0.18033688011112043f;   // (1/8) * log2(e), folded into Q'

    // ---- zero scratch ----
    if (tid < 4) *(unsigned int*)(smem + tid*2) = 0u;

    // ---- stage Wo f16 [64 o][72] (single b128 write) ----
    {
        int o = tid >> 3, c8 = tid & 7;
        const float* ws = Wo + o*64 + c8*8;
        float4 a = *(const float4*)ws;
        float4 d = *(const float4*)(ws + 4);
        *(uint4*)(smem + WB + o*72 + c8*8) =
            make_uint4(pk2(a.x,a.y), pk2(a.z,a.w), pk2(d.x,d.y), pk2(d.z,d.w));
    }

    // ---- stage projected K', Q' (x sc), V'^T as f16 (2 cells/thread) ----
    {
        // hoist all 12 global loads first (MLP)
        float4 L[12];
        int cn_[2], ch_[2];
        #pragma unroll
        for (int i = 0; i < 2; ++i){
            int id = i*512 + tid;
            int cn = id >> 3, ch = id & 7;
            cn_[i] = cn; ch_[i] = ch;
            const float* pk = K + base + cn*4096 + ch*8;
            const float* pv = V + base + cn*4096 + ch*8;
            const float* pq = Q + base + cn*4096 + ch*8;
            L[i*6+0] = *(const float4*)pk;  L[i*6+1] = *(const float4*)(pk+4);
            L[i*6+2] = *(const float4*)pv;  L[i*6+3] = *(const float4*)(pv+4);
            L[i*6+4] = *(const float4*)pq;  L[i*6+5] = *(const float4*)(pq+4);
        }
        #pragma unroll
        for (int i = 0; i < 2; ++i){
            int cn = cn_[i], ch = ch_[i];
            float4 ka = L[i*6+0], kb = L[i*6+1];
            float4 va = L[i*6+2], vb = L[i*6+3];
            float4 qa = L[i*6+4], qb = L[i*6+5];
            float ok[8], ov[8], oq[8];
            #pragma unroll
            for (int e = 0; e < 8; ++e){
                float4 wk0 = *(const float4*)(Wk + e*8), wk1 = *(const float4*)(Wk + e*8 + 4);
                float4 wv0 = *(const float4*)(Wv + e*8), wv1 = *(const float4*)(Wv + e*8 + 4);
                float4 wq0 = *(const float4*)(Wq + e*8), wq1 = *(const float4*)(Wq + e*8 + 4);
                ok[e] = ka.x*wk0.x + ka.y*wk0.y + ka.z*wk0.z + ka.w*wk0.w
                      + kb.x*wk1.x + kb.y*wk1.y + kb.z*wk1.z + kb.w*wk1.w;
                ov[e] = va.x*wv0.x + va.y*wv0.y + va.z*wv0.z + va.w*wv0.w
                      + vb.x*wv1.x + vb.y*wv1.y + vb.z*wv1.z + vb.w*wv1.w;
                oq[e] = (qa.x*wq0.x + qa.y*wq0.y + qa.z*wq0.z + qa.w*wq0.w
                      +  qb.x*wq1.x + qb.y*wq1.y + qb.z*wq1.z + qb.w*wq1.w) * SC;
            }
            *(uint4*)(smem + KB + ch*1024 + cn*8) =
                make_uint4(pk2(ok[0],ok[1]), pk2(ok[2],ok[3]), pk2(ok[4],ok[5]), pk2(ok[6],ok[7]));
            *(uint4*)(smem + QB + ch*1024 + cn*8) =
                make_uint4(pk2(oq[0],oq[1]), pk2(oq[2],oq[3]), pk2(oq[4],oq[5]), pk2(oq[6],oq[7]));
            #pragma unroll
            for (int e = 0; e < 8; ++e)
                smem[VB + ch*1024 + e*128 + cn] = f2h(ov[e]);
        }
    }

    __syncthreads();

    // ---- attention: wave = head h ----
    const int h    = tid >> 6;
    const int q16  = tid & 15;          // lane & 15
    const int quad = (tid & 63) >> 4;   // lane >> 4
    const f32x4 zz = {0.f, 0.f, 0.f, 0.f};

    // K' A-fragments (8 m-tiles): A[m=l&15][k=quad*4+i], quads 2,3 -> zero
    half4 kf[8];
    #pragma unroll
    for (int mt = 0; mt < 8; ++mt){
        int a = KB + h*1024 + (mt*16 + q16)*8 + quad*4;
        if (quad >= 2) a = ZS;
        kf[mt] = *(const half4*)(smem + a);
    }
    // V'^T B-fragments (8 k-steps): B[k=quad*4+i][n=e=l&15], e>=8 -> zero
    half4 vf[8];
    #pragma unroll
    for (int s = 0; s < 8; ++s){
        int a = VB + h*1024 + q16*128 + s*16 + quad*4;
        if (q16 >= 8) a = ZS;
        vf[s] = *(const half4*)(smem + a);
    }
    // Q' B-fragments for all 8 strips (prefetched): B[k=d][n=q], quads 2,3 -> zero
    half4 qf[8];
    #pragma unroll
    for (int qs = 0; qs < 8; ++qs){
        int a = QB + h*1024 + (qs*16 + q16)*8 + quad*4;
        if (quad >= 2) a = ZS;
        qf[qs] = *(const half4*)(smem + a);
    }

    #pragma unroll 1
    for (int qs = 0; qs < 8; ++qs){
        // E^T strip: 8 independent MFMAs (m-tile = key tile)
        f32x4 acc[8];
        #pragma unroll
        for (int mt = 0; mt < 8; ++mt)
            acc[mt] = MFMA16(kf[mt], qf[qs], zz);

        // exp2 (E pre-scaled; clamp is pure safety, P stays f16-safe)
        float s = 0.f;
        #pragma unroll
        for (int mt = 0; mt < 8; ++mt){
            #pragma unroll
            for (int r = 0; r < 4; ++r){
                float p = __builtin_amdgcn_exp2f(fminf(acc[mt][r], 14.f));
                acc[mt][r] = p;
                s += p;
            }
        }

        // pack UNNORMALIZED P into A-fragments (normalization deferred past PV)
        union { uint2 u; half4 hp; } pf[8];
        #pragma unroll
        for (int mt = 0; mt < 8; ++mt)
            pf[mt].u = make_uint2(pk2(acc[mt][0], acc[mt][1]),
                                  pk2(acc[mt][2], acc[mt][3]));

        // s-reduction: lane's 32 p-values share query = q16; reduce across quads
        s += __shfl_xor(s, 16, 64);
        s += __shfl_xor(s, 32, 64);
        float inv = 1.0f / s;
        // PV output rows are queries quad*4+r -> fetch those queries' normalizers
        // (lanes 0..15 hold per-query inv post-reduction). Overlaps the PV chain.
        float invr[4];
        #pragma unroll
        for (int r = 0; r < 4; ++r)
            invr[r] = __shfl(inv, quad*4 + r, 64);

        // PV: chained accumulation over 8 k-steps
        f32x4 o = zz;
        #pragma unroll
        for (int s8 = 0; s8 < 8; ++s8)
            o = MFMA16(pf[s8].hp, vf[s8], o);

        // write normalized C' strip: lane holds out[q=quad*4+r][e=l&15<8]
        if (q16 < 8){
            #pragma unroll
            for (int r = 0; r < 4; ++r){
                int row = qs*16 + quad*4 + r;
                smem[CB + row*72 + h*8 + q16] = f2h(o[r] * invr[r]);
            }
        }
    }

    __syncthreads();

    // ---- fc: wave w handles output rows w*16..w*16+15 ----
    const int w = h;
    half4 af[4];
    #pragma unroll
    for (int ks = 0; ks < 4; ++ks)
        af[ks] = *(const half4*)(smem + CB + (w*16 + q16)*72 + ks*16 + quad*4);

    #pragma unroll
    for (int nt = 0; nt < 4; ++nt){
        f32x4 a = zz;
        #pragma unroll
        for (int ks = 0; ks < 4; ++ks){
            half4 bf = *(const half4*)(smem + WB + (nt*16 + q16)*72 + ks*16 + quad*4);
            a = MFMA16(af[ks], bf, a);
        }
        float bb = bo[nt*16 + q16];
        #pragma unroll
        for (int r = 0; r < 4; ++r){
            int row = w*16 + quad*4 + r;
            Out[base + (long)row*4096 + nt*16 + q16] = a[r] + bb;
        }
    }
}

extern "C" void kernel_launch(void* const* d_in, const int* in_sizes, int n_in,
                              void* d_out, int out_size, void* d_ws, size_t ws_size,
                              hipStream_t stream)
{
    const float* V  = (const float*)d_in[0];
    const float* K  = (const float*)d_in[1];
    const float* Q  = (const float*)d_in[2];
    const float* Wv = (const float*)d_in[3];
    const float* Wk = (const float*)d_in[4];
    const float* Wq = (const float*)d_in[5];
    const float* Wo = (const float*)d_in[6];
    const float* bo = (const float*)d_in[7];

    sattn_kernel<<<dim3(512), dim3(512), 0, stream>>>(
        V, K, Q, Wv, Wk, Wq, Wo, bo, (float*)d_out);
}